// Round 6
// baseline (441.625 us; speedup 1.0000x reference)
//
#include <hip/hip_runtime.h>
#include <math.h>

// Problem constants: [b, seq, heads, head_dim] = [4, 8192, 16, 64], f32.
#define BB 4
#define SS 8192
#define HH 16
#define DDIM 64

// ws layout (floats): [0, 6144) sums[3][4][8][64]  (group, batch, qh pad 8, d)
// X buffers are GONE — pass 2 recomputes attention instead of reading X back.
static const long WS_FLOATS = 6144;

__global__ __launch_bounds__(256) void k_zero_sums(float* ws) {
    int idx = blockIdx.x * 256 + threadIdx.x;
    if (idx < 6144) ws[idx] = 0.0f;
}

__device__ __forceinline__ float4 shfl_xor4(float4 v, int m) {
    return make_float4(__shfl_xor(v.x, m, 64), __shfl_xor(v.y, m, 64),
                       __shfl_xor(v.z, m, 64), __shfl_xor(v.w, m, 64));
}

// Pass 1: sums only. Identical to the best-measured (109 us) r0 k_attn with
// the X store deleted: per-position head-group attention, butterfly-reduced
// scores, PV, cross-position reduce, one atomic per (qh,d) per block.
// Lane layout: lane = (posInWave<<4) | d4 -> 16 lanes own one position's 64-d.
__global__ __launch_bounds__(256) void k_attn_sums(const float* __restrict__ Q,
                                                   const float* __restrict__ Kp,
                                                   const float* __restrict__ Vp,
                                                   float* __restrict__ ws) {
    __shared__ __align__(16) float psum[4][6][64];  // wave, qh, d

    int bid = blockIdx.x;
    int gi, b, tile, g, r, off, hmin;
    if (bid < 2048)      { gi = 0; b = bid >> 9; tile = bid & 511; g = 6; r = 1; off = 0; hmin = 0;  }
    else if (bid < 3072) { gi = 1; bid -= 2048; b = bid >> 8; tile = bid & 255; g = 5; r = 2; off = 1; hmin = 5;  }
    else                 { gi = 2; bid -= 3072; b = bid >> 7; tile = bid & 127; g = 5; r = 4; off = 2; hmin = 10; }

    const int t = threadIdx.x;
    const int lane = t & 63;
    const int wave = t >> 6;
    const int d4 = t & 15;
    const int pIdx = t >> 4;
    const int j = tile * 16 + pIdx;
    const int pos = off + j * r;

    const long rowbase = (((long)b * SS + pos) * HH + hmin) * DDIM;
    const float4* q4p = (const float4*)(Q + rowbase);
    const float4* k4p = (const float4*)(Kp + rowbase);
    const float4* v4p = (const float4*)(Vp + rowbase);

    float4 q4[6], k4[6], v4[6];
#pragma unroll
    for (int hh = 0; hh < 6; ++hh) {
        if (hh < g) {
            q4[hh] = q4p[hh * 16 + d4];
            k4[hh] = k4p[hh * 16 + d4];
            v4[hh] = v4p[hh * 16 + d4];
        } else {
            q4[hh] = make_float4(0.f, 0.f, 0.f, 0.f);
            k4[hh] = q4[hh];
            v4[hh] = q4[hh];
        }
    }

    float p[6][6];
#pragma unroll
    for (int qh = 0; qh < 6; ++qh) {
#pragma unroll
        for (int kh = 0; kh < 6; ++kh) {
            if (qh < g && kh < g) {
                float s = q4[qh].x * k4[kh].x + q4[qh].y * k4[kh].y +
                          q4[qh].z * k4[kh].z + q4[qh].w * k4[kh].w;
#pragma unroll
                for (int m = 1; m <= 8; m <<= 1) s += __shfl_xor(s, m, 64);
                p[qh][kh] = s;
            } else {
                p[qh][kh] = 0.0f;
            }
        }
    }

#pragma unroll
    for (int qh = 0; qh < 6; ++qh) {
        if (qh >= g) continue;
        float mx = -3.4e38f;
#pragma unroll
        for (int kh = 0; kh < 6; ++kh)
            if (kh < g) mx = fmaxf(mx, p[qh][kh]);
        float den = 0.0f;
#pragma unroll
        for (int kh = 0; kh < 6; ++kh) {
            if (kh < g) { p[qh][kh] = __expf((p[qh][kh] - mx) * 0.125f); den += p[qh][kh]; }
        }
        float rden = 1.0f / den;
#pragma unroll
        for (int kh = 0; kh < 6; ++kh) p[qh][kh] *= rden;
    }

#pragma unroll
    for (int qh = 0; qh < 6; ++qh) {
        if (qh >= g) continue;
        float4 o = make_float4(0.f, 0.f, 0.f, 0.f);
#pragma unroll
        for (int kh = 0; kh < 6; ++kh) {
            if (kh < g) {
                o.x += p[qh][kh] * v4[kh].x; o.y += p[qh][kh] * v4[kh].y;
                o.z += p[qh][kh] * v4[kh].z; o.w += p[qh][kh] * v4[kh].w;
            }
        }
        // NO X store — sums only.
        float4 red = o;
#pragma unroll
        for (int m = 16; m <= 32; m <<= 1) {
            float4 tmp = shfl_xor4(red, m);
            red.x += tmp.x; red.y += tmp.y; red.z += tmp.z; red.w += tmp.w;
        }
        if (lane < 16) ((float4*)&psum[wave][qh][0])[d4] = red;
    }
    __syncthreads();

    for (int idx = t; idx < g * 64; idx += 256) {
        int qh = idx >> 6, dd = idx & 63;
        float v = psum[0][qh][dd] + psum[1][qh][dd] + psum[2][qh][dd] + psum[3][qh][dd];
        unsafeAtomicAdd(ws + ((long)(gi * 4 + b) * 8 + qh) * 64 + dd, v);
    }
}

// One group's attention for this lane's position: heads [HMIN, HMIN+G) of
// (b,pos). Returns o[G] (this lane's float4 of each output head row).
// Caller guarantees the whole 16-lane row shares the active predicate.
template<int G>
__device__ __forceinline__ void attn_one(const float* __restrict__ Q,
                                         const float* __restrict__ Kp,
                                         const float* __restrict__ Vp,
                                         long base16, int hmin, int d4,
                                         float4* o) {
    const float4* q4p = (const float4*)Q + base16 + (long)hmin * 16;
    const float4* k4p = (const float4*)Kp + base16 + (long)hmin * 16;
    const float4* v4p = (const float4*)Vp + base16 + (long)hmin * 16;

    float4 q4[G], k4[G];
#pragma unroll
    for (int hh = 0; hh < G; ++hh) {
        q4[hh] = q4p[hh * 16 + d4];
        k4[hh] = k4p[hh * 16 + d4];
    }
    float p[G][G];
#pragma unroll
    for (int qh = 0; qh < G; ++qh)
#pragma unroll
        for (int kh = 0; kh < G; ++kh) {
            float s = q4[qh].x * k4[kh].x + q4[qh].y * k4[kh].y +
                      q4[qh].z * k4[kh].z + q4[qh].w * k4[kh].w;
#pragma unroll
            for (int m = 1; m <= 8; m <<= 1) s += __shfl_xor(s, m, 64);
            p[qh][kh] = s;
        }
#pragma unroll
    for (int qh = 0; qh < G; ++qh) {
        float mx = -3.4e38f;
#pragma unroll
        for (int kh = 0; kh < G; ++kh) mx = fmaxf(mx, p[qh][kh]);
        float den = 0.0f;
#pragma unroll
        for (int kh = 0; kh < G; ++kh) {
            p[qh][kh] = __expf((p[qh][kh] - mx) * 0.125f);
            den += p[qh][kh];
        }
        float rden = 1.0f / den;
#pragma unroll
        for (int kh = 0; kh < G; ++kh) p[qh][kh] *= rden;
    }
    float4 v4[G];
#pragma unroll
    for (int kh = 0; kh < G; ++kh) v4[kh] = v4p[kh * 16 + d4];
#pragma unroll
    for (int qh = 0; qh < G; ++qh) {
        float4 acc = make_float4(0.f, 0.f, 0.f, 0.f);
#pragma unroll
        for (int kh = 0; kh < G; ++kh) {
            acc.x += p[qh][kh] * v4[kh].x; acc.y += p[qh][kh] * v4[kh].y;
            acc.z += p[qh][kh] * v4[kh].z; acc.w += p[qh][kh] * v4[kh].w;
        }
        o[qh] = acc;
    }
}

// Pass 2: recompute attention per position for every group that touches it,
// normalize with finalized sums (LDS-staged reciprocals), write complete
// 16-head output rows with plain coalesced stores. No X, no atomics.
// Block = 16 consecutive positions of one batch; lane=(posInWave<<4)|d4.
__global__ __launch_bounds__(256) void k_fused(const float* __restrict__ Q,
                                               const float* __restrict__ Kp,
                                               const float* __restrict__ Vp,
                                               const float* __restrict__ ws,
                                               float* __restrict__ out) {
    __shared__ __align__(16) float rsm[3][6][64];   // 1/sums for this batch

    const int t = threadIdx.x;
    const int bid = blockIdx.x;
    const int b = bid >> 9;                 // 512 tiles per batch
    const int pos0 = (bid & 511) * 16;

    for (int i = t; i < 3 * 6 * 64; i += 256) {
        const int gi = i / 384, rem = i - gi * 384;
        const int qh = rem >> 6, dd = rem & 63;
        rsm[gi][qh][dd] = __frcp_rn(ws[((long)(gi * 4 + b) * 8 + qh) * 64 + dd]);
    }
    __syncthreads();

    const int d4 = t & 15;
    const int pIdx = t >> 4;
    const int pos = pos0 + pIdx;
    const bool odd = (pos & 1) == 1;        // group 1 active
    const bool m42 = (pos & 3) == 2;        // group 2 active
    const long base16 = ((long)b * SS + pos) * HH * 16;  // float4 idx of (b,pos,0,0)

    float4 o0[6], o1[5], o2[5];
#pragma unroll
    for (int i = 0; i < 5; ++i) { o1[i] = make_float4(0.f, 0.f, 0.f, 0.f); o2[i] = o1[i]; }

    attn_one<6>(Q, Kp, Vp, base16, 0, d4, o0);          // heads 0..5, all pos
    if (odd) attn_one<5>(Q, Kp, Vp, base16, 5, d4, o1); // heads 5..9, odd pos
    if (m42) attn_one<5>(Q, Kp, Vp, base16, 10, d4, o2); // heads 10..14, pos%4==2

    // ---- combine + write full 16-head row (plain stores, 256B bursts) ----
    const float third = 1.0f / 3.0f;
    float4* orow = (float4*)out + base16;
#pragma unroll
    for (int h = 0; h < 16; ++h) {
        float4 rcp, x;
        bool have = false;
        if (h < 5) {            // g0 only
            rcp = ((const float4*)&rsm[0][h][0])[d4]; x = o0[h]; have = true;
        } else if (h == 5) {    // g0 (+ g1 at odd pos)
            rcp = ((const float4*)&rsm[0][5][0])[d4]; x = o0[5]; have = true;
        } else if (h < 10) {    // g1 only (odd pos)
            rcp = ((const float4*)&rsm[1][h - 5][0])[d4]; x = o1[h - 5]; have = odd;
        } else if (h < 15) {    // g2 only (pos%4==2)
            rcp = ((const float4*)&rsm[2][h - 10][0])[d4]; x = o2[h - 10]; have = m42;
        }
        float4 st = make_float4(0.f, 0.f, 0.f, 0.f);
        if (have) {
            st.x = x.x * rcp.x * third; st.y = x.y * rcp.y * third;
            st.z = x.z * rcp.z * third; st.w = x.w * rcp.w * third;
        }
        if (h == 5 && odd) {    // add g1's head-5 contribution in-register
            float4 r1 = ((const float4*)&rsm[1][0][0])[d4];
            st.x += o1[0].x * r1.x * third; st.y += o1[0].y * r1.y * third;
            st.z += o1[0].z * r1.z * third; st.w += o1[0].w * r1.w * third;
        }
        orow[h * 16 + d4] = st;
    }
}

extern "C" void kernel_launch(void* const* d_in, const int* in_sizes, int n_in,
                              void* d_out, int out_size, void* d_ws, size_t ws_size,
                              hipStream_t stream) {
    const float* Q = (const float*)d_in[0];
    const float* K = (const float*)d_in[1];
    const float* V = (const float*)d_in[2];
    float* ws = (float*)d_ws;
    float* out = (float*)d_out;

    if (ws_size < (size_t)WS_FLOATS * sizeof(float)) return;  // needs only 24 KB

    k_zero_sums<<<24, 256, 0, stream>>>(ws);
    k_attn_sums<<<3584, 256, 0, stream>>>(Q, K, V, ws);
    k_fused<<<2048, 256, 0, stream>>>(Q, K, V, ws, out);
}